// Round 4
// baseline (151.045 us; speedup 1.0000x reference)
//
#include <hip/hip_runtime.h>
#include <hip/hip_fp16.h>

constexpr int Bc  = 4;
constexpr int Cc  = 64;
constexpr int H0  = 128;
constexpr int W0  = 128;
constexpr int HW  = H0 * W0;
constexpr int Gc  = 4;
constexpr int CG  = Cc / Gc;     // 16
constexpr int HOc = H0 * 2;      // 256
constexpr int WOc = W0 * 2;      // 256

constexpr int TW = 16;           // output tile width
constexpr int TH = 8;            // output tile height
constexpr int HX = TW + 2;       // 18 halo cols
constexpr int HY = TH + 2;       // 10 halo rows
constexpr int NHALO = HX * HY;   // 180
constexpr int NTASK = Gc * NHALO;// 720

constexpr int SXC = 10;          // staged input cols (ox/2-1 .. ox/2+8)
constexpr int SYC = 6;           // staged input rows (oy/2-1 .. oy/2+4)
constexpr int SN  = SXC * SYC;   // 60 floats per channel
constexpr int NROW = Gc * 8;     // 32 offset rows (g*8 + sy*4+sx*2+d)

constexpr int NTILE = (HOc / TH) * (WOc / TW);  // 512 tiles per batch
constexpr int NB    = NTILE * Bc;               // 2048 blocks

__device__ __forceinline__ void gl_lds4(const float* g, float* l) {
    __builtin_amdgcn_global_load_lds(
        (const __attribute__((address_space(1))) void*)g,
        (__attribute__((address_space(3)))       void*)l, 4, 0, 0);
}

// ---------------------------------------------------------------------------
// Fully fused: stage x window (async) -> offsets in LDS -> bilinear fp16 halo
// -> sk/km + softmax -> 3x3 dynamic conv. One block = 16x8 output tile.
// LDS 46.1 KB -> 3 blocks/CU.
// ---------------------------------------------------------------------------
__global__ __launch_bounds__(256, 3) void k1_fused(
    const float* __restrict__ x,
    const float* __restrict__ w_off,  const float* __restrict__ b_off,
    const float* __restrict__ w_offm, const float* __restrict__ b_offm,
    const float* __restrict__ w_sk,   const float* __restrict__ b_sk,
    const float* __restrict__ w_km,   const float* __restrict__ b_km,
    float* __restrict__ out)
{
    __shared__ __half xd[Cc][NHALO];      // 23040 B: deformed halo, fp16
    __shared__ float  offs[NROW][SN];     //  7680 B: gated offsets per window pos
    __shared__ float  ovl[Cc * SN];       // 15360 B: xstage, later kmb|sknb
    float* xstage = ovl;                  // [c][60]
    float* kmb    = ovl;                  // [128][9]
    float* sknb   = ovl + 128 * 9;        // [128][9]

    // XCD-aware swizzle: 2048 blocks, 8 XCDs -> contiguous 256-block chunks
    const int bid  = blockIdx.x;
    const int sw   = (bid & 7) * (NB / 8) + (bid >> 3);
    const int b    = sw >> 9;             // / 512
    const int tile = sw & 511;
    const int ox = (tile & 15) * TW;
    const int oy = (tile >> 4) * TH;
    const int t  = threadIdx.x;
    const int syr = (oy >> 1) - 1;        // staged window origin (input coords)
    const int sxr = (ox >> 1) - 1;

    const float* xb = x + (size_t)b * Cc * HW;

    // ---- phase A: async-stage 6x10 input window, 64 ch (border-clamped) ----
    for (int i = t; i < Cc * SN; i += 256) {          // 15 iters, all async
        const int c   = i / SN;
        const int rem = i - c * SN;
        const int r   = rem / SXC;
        const int j   = rem - r * SXC;
        const int yy  = min(max(syr + r, 0), H0 - 1);
        const int xx  = min(max(sxr + j, 0), W0 - 1);
        gl_lds4(xb + (size_t)c * HW + yy * W0 + xx, &xstage[i]);
    }
    __syncthreads();   // drains vmcnt + barrier

    // ---- phase A': gated offset conv for all 60 positions x 32 rows ----
    // wave w computes rows [w*8, w*8+8); lane = window position.
    {
        const int wave = t >> 6, lane = t & 63;
        if (lane < SN) {
            const int R0 = wave * 8;
            float a[8], m[8];
#pragma unroll
            for (int q = 0; q < 8; ++q) { a[q] = 0.f; m[q] = 0.f; }
            for (int c = 0; c < Cc; ++c) {
                const float xv = xstage[c * SN + lane];
#pragma unroll
                for (int q = 0; q < 8; ++q) {
                    a[q] = fmaf(w_off [(R0 + q) * Cc + c], xv, a[q]);  // s_load
                    m[q] = fmaf(w_offm[(R0 + q) * Cc + c], xv, m[q]);
                }
            }
#pragma unroll
            for (int q = 0; q < 8; ++q) {
                const float av = a[q] + b_off [R0 + q];
                const float mv = m[q] + b_offm[R0 + q];
                offs[R0 + q][lane] = av / (1.f + __expf(-mv));
            }
        }
    }
    __syncthreads();

    // ---- phase B: bilinear sample halo -> xd (fp16), offsets from LDS ----
    for (int task = t; task < NTASK; task += 256) {
        const int g   = task / NHALO;
        const int pix = task - g * NHALO;
        const int hy  = pix / HX;
        const int hx  = pix - hy * HX;
        const int gy  = oy - 1 + hy;
        const int gx  = ox - 1 + hx;
        if (gy < 0 || gy >= HOc || gx < 0 || gx >= WOc) {
#pragma unroll 4
            for (int c = 0; c < CG; ++c) xd[g * CG + c][pix] = __half(0.f);
            continue;
        }
        const int sy = gy & 1, sx = gx & 1;
        const int h  = gy >> 1, w  = gx >> 1;
        const int r0 = sy * 4 + sx * 2;
        const int pos = (h - syr) * SXC + (w - sxr);
        const float offx = offs[g * 8 + r0    ][pos];
        const float offy = offs[g * 8 + r0 + 1][pos];

        float ix = ((float)gx + 0.5f + offx) * 0.5f - 0.5f;
        float iy = ((float)gy + 0.5f + offy) * 0.5f - 0.5f;
        ix = fminf(fmaxf(ix, 0.f), (float)(W0 - 1));
        iy = fminf(fmaxf(iy, 0.f), (float)(H0 - 1));
        const float x0f = floorf(ix), y0f = floorf(iy);
        const float wx = ix - x0f,   wy = iy - y0f;
        const int x0 = (int)x0f, y0 = (int)y0f;
        const int x1 = min(x0 + 1, W0 - 1), y1 = min(y0 + 1, H0 - 1);
        const float w00 = (1.f - wx) * (1.f - wy);
        const float w01 = wx * (1.f - wy);
        const float w10 = (1.f - wx) * wy;
        const float w11 = wx * wy;

        const int j0 = x0 - sxr, j1 = x1 - sxr;
        const int i0 = y0 - syr, i1 = y1 - syr;
        const bool inl = (j0 >= 0) & (j1 < SXC) & (i0 >= 0) & (i1 < SYC);

        if (inl) {
            const int o00 = i0 * SXC + j0, o01 = i0 * SXC + j1;
            const int o10 = i1 * SXC + j0, o11 = i1 * SXC + j1;
            const float* s = xstage + (g * CG) * SN;
#pragma unroll 4
            for (int c = 0; c < CG; ++c) {
                const float* pc = s + c * SN;
                const float v = w00 * pc[o00] + w01 * pc[o01]
                              + w10 * pc[o10] + w11 * pc[o11];
                xd[g * CG + c][pix] = __float2half(v);
            }
        } else {  // rare: tap escaped staged window -> global
            const int o00 = y0 * W0 + x0, o01 = y0 * W0 + x1;
            const int o10 = y1 * W0 + x0, o11 = y1 * W0 + x1;
            const float* xg = xb + (size_t)(g * CG) * HW;
#pragma unroll 4
            for (int c = 0; c < CG; ++c) {
                const float* pc = xg + (size_t)c * HW;
                const float v = w00 * pc[o00] + w01 * pc[o01]
                              + w10 * pc[o10] + w11 * pc[o11];
                xd[g * CG + c][pix] = __float2half(v);
            }
        }
    }
    __syncthreads();

    // ---- phase C: sk/km dots (wave-split), gate + softmax -> sknb ----
    {
        const int p   = t & 127;
        const int ctr = ((p >> 4) + 1) * HX + (p & 15) + 1;
        float acc[9];
#pragma unroll
        for (int k = 0; k < 9; ++k) acc[k] = 0.f;

        if (t < 128) {
            for (int c = 0; c < Cc; ++c) {
                const float xv = __half2float(xd[c][ctr]);
#pragma unroll
                for (int k = 0; k < 9; ++k)
                    acc[k] = fmaf(w_sk[k * Cc + c], xv, acc[k]);  // s_load
            }
        } else {
            for (int c = 0; c < Cc; ++c) {
                const float xv = __half2float(xd[c][ctr]);
#pragma unroll
                for (int k = 0; k < 9; ++k)
                    acc[k] = fmaf(w_km[k * Cc + c], xv, acc[k]);
            }
#pragma unroll
            for (int k = 0; k < 9; ++k) kmb[p * 9 + k] = acc[k];
        }
        __syncthreads();

        if (t < 128) {
            float sv[9], mx = -1e30f;
#pragma unroll
            for (int k = 0; k < 9; ++k) {
                const float z = kmb[p * 9 + k] + b_km[k];
                sv[k] = (acc[k] + b_sk[k]) / (1.f + __expf(-z));
                mx = fmaxf(mx, sv[k]);
            }
            float sum = 0.f;
#pragma unroll
            for (int k = 0; k < 9; ++k) { sv[k] = __expf(sv[k] - mx); sum += sv[k]; }
            const float inv = 1.f / sum;
#pragma unroll
            for (int k = 0; k < 9; ++k) sknb[p * 9 + k] = sv[k] * inv;
        }
    }
    __syncthreads();

    // ---- phase D: 3x3 dynamic conv, 2x2 pixel register blocking ----
    {
        const int sq    = t & 31;         // 8x4 squares of 2x2 pixels
        const int chunk = t >> 5;         // 8 channel chunks
        const int sqx = sq & 7, sqy = sq >> 3;
        const int hx0 = 2 * sqx, hy0 = 2 * sqy;
        const int p00 = (2 * sqy) * TW + 2 * sqx;

        float s00[9], s01[9], s10[9], s11[9];
#pragma unroll
        for (int k = 0; k < 9; ++k) {
            s00[k] = sknb[p00 * 9 + k];        s01[k] = sknb[(p00 + 1) * 9 + k];
            s10[k] = sknb[(p00 + TW) * 9 + k]; s11[k] = sknb[(p00 + TW + 1) * 9 + k];
        }
        const int orow0 = oy + 2 * sqy, ocol0 = ox + 2 * sqx;

#pragma unroll 2
        for (int i = 0; i < 8; ++i) {
            const int c = chunk * 8 + i;
            const __half* xc = &xd[c][0];
            float wd[4][4];
#pragma unroll
            for (int ry = 0; ry < 4; ++ry) {
                const int base = (hy0 + ry) * HX + hx0;
                const __half2 u0 = *reinterpret_cast<const __half2*>(&xc[base]);
                const __half2 u1 = *reinterpret_cast<const __half2*>(&xc[base + 2]);
                const float2 f0 = __half22float2(u0);
                const float2 f1 = __half22float2(u1);
                wd[ry][0] = f0.x; wd[ry][1] = f0.y; wd[ry][2] = f1.x; wd[ry][3] = f1.y;
            }
            float a00 = 0.f, a01 = 0.f, a10 = 0.f, a11 = 0.f;
#pragma unroll
            for (int ky = 0; ky < 3; ++ky)
#pragma unroll
                for (int kx = 0; kx < 3; ++kx) {
                    const int k = ky * 3 + kx;
                    a00 = fmaf(s00[k], wd[ky    ][kx    ], a00);
                    a01 = fmaf(s01[k], wd[ky    ][kx + 1], a01);
                    a10 = fmaf(s10[k], wd[ky + 1][kx    ], a10);
                    a11 = fmaf(s11[k], wd[ky + 1][kx + 1], a11);
                }
            float* ob = out + ((size_t)(b * Cc + c)) * (HOc * WOc)
                            + (size_t)orow0 * WOc + ocol0;
            *reinterpret_cast<float2*>(ob)       = make_float2(a00, a01);
            *reinterpret_cast<float2*>(ob + WOc) = make_float2(a10, a11);
        }
    }
}

// ---------------------------------------------------------------------------
extern "C" void kernel_launch(void* const* d_in, const int* in_sizes, int n_in,
                              void* d_out, int out_size, void* d_ws, size_t ws_size,
                              hipStream_t stream)
{
    const float* x      = (const float*)d_in[0];
    const float* w_off  = (const float*)d_in[1];
    const float* b_off  = (const float*)d_in[2];
    const float* w_offm = (const float*)d_in[3];
    const float* b_offm = (const float*)d_in[4];
    const float* w_sk   = (const float*)d_in[5];
    const float* b_sk   = (const float*)d_in[6];
    const float* w_km   = (const float*)d_in[7];
    const float* b_km   = (const float*)d_in[8];
    float* outp = (float*)d_out;

    dim3 blk(256);
    dim3 g1(NB);                          // 2048 blocks, XCD-swizzled in-kernel
    hipLaunchKernelGGL(k1_fused, g1, blk, 0, stream,
                       x, w_off, b_off, w_offm, b_offm,
                       w_sk, b_sk, w_km, b_km, outp);
}

// Round 5
// 118.935 us; speedup vs baseline: 1.2700x; 1.2700x over previous
//
#include <hip/hip_runtime.h>
#include <hip/hip_fp16.h>

constexpr int Bc  = 4;
constexpr int Cc  = 64;
constexpr int H0  = 128;
constexpr int W0  = 128;
constexpr int HW  = H0 * W0;
constexpr int Gc  = 4;
constexpr int CG  = Cc / Gc;     // 16
constexpr int HOc = H0 * 2;      // 256
constexpr int WOc = W0 * 2;      // 256

constexpr int TW = 16;           // output tile width
constexpr int TH = 8;            // output tile height
constexpr int HX = TW + 2;       // 18 halo cols
constexpr int HY = TH + 2;       // 10 halo rows
constexpr int NHALO = HX * HY;   // 180
constexpr int NTASK = Gc * NHALO;// 720

constexpr int SXC = 10;          // staged input cols (ox/2-1 .. ox/2+8)
constexpr int SYC = 6;           // staged input rows (oy/2-1 .. oy/2+4)
constexpr int SN  = SXC * SYC;   // 60 elems per channel

constexpr int NTILE = (HOc / TH) * (WOc / TW);  // 512 tiles per batch
constexpr int NB    = NTILE * Bc;               // 2048 blocks

// ---------------------------------------------------------------------------
// k0: gated offset conv. Block = 128 pixels x 2 roles (w_off / w_offm wave-pairs).
// Weights transposed into LDS -> broadcast ds_read_b128, no s_load stream.
// x read ONCE per batch. Output: half2 (offx,offy) per (b, pair, pixel), 4 MB.
// Row index R = g*8 + sy*4 + sx*2 + d; pair rp = R>>1 = g*4 + sy*2 + sx.
// ---------------------------------------------------------------------------
__global__ __launch_bounds__(256) void k0_offsets(
    const float* __restrict__ x,
    const float* __restrict__ w_off,  const float* __restrict__ b_off,
    const float* __restrict__ w_offm, const float* __restrict__ b_offm,
    __half2* __restrict__ offbuf)
{
    __shared__ float wT[2][Cc][32];     // [mat][c][row] = 16 KB
    __shared__ float sig[128][33];      // sigmoid exchange, padded stride

    const int b    = blockIdx.y;
    const int t    = threadIdx.x;
    const int role = t >> 7;            // waves 0,1: w_off ; waves 2,3: w_offm
    const int pl   = t & 127;
    const int px   = blockIdx.x * 128 + pl;

    // stage transposed weights (16 KB, L2-hot after first blocks)
    for (int i = t; i < 2 * Cc * 32; i += 256) {
        const int mat = i >> 11;
        const int c   = (i >> 5) & 63;
        const int r   = i & 31;
        wT[mat][c][r] = (mat ? w_offm : w_off)[r * Cc + c];
    }
    __syncthreads();

    float acc[32];
#pragma unroll
    for (int r = 0; r < 32; ++r) acc[r] = 0.f;

    const float* xp = x + (size_t)b * Cc * HW + px;
    for (int c = 0; c < Cc; ++c) {
        const float xv = xp[c * HW];                 // coalesced, once per b
        const float* wr = &wT[role][c][0];           // broadcast b128 reads
#pragma unroll
        for (int r = 0; r < 32; ++r)
            acc[r] = fmaf(wr[r], xv, acc[r]);
    }

    if (role == 1) {
#pragma unroll
        for (int r = 0; r < 32; ++r)
            sig[pl][r] = 1.f / (1.f + __expf(-(acc[r] + b_offm[r])));
    }
    __syncthreads();

    if (role == 0) {
#pragma unroll
        for (int rp = 0; rp < 16; ++rp) {
            const float vx = (acc[2 * rp]     + b_off[2 * rp])     * sig[pl][2 * rp];
            const float vy = (acc[2 * rp + 1] + b_off[2 * rp + 1]) * sig[pl][2 * rp + 1];
            offbuf[((size_t)b * 16 + rp) * HW + px] = __floats2half2_rn(vx, vy);
        }
    }
}

// ---------------------------------------------------------------------------
// k1_fused: stage x window (fp16) -> bilinear fp16 halo -> sk/km + softmax
// -> 3x3 dynamic conv. Block = 16x8 output tile. LDS 31.5 KB -> 5 blocks/CU.
// ---------------------------------------------------------------------------
__global__ __launch_bounds__(256, 5) void k1_fused(
    const float* __restrict__ x, const __half2* __restrict__ offbuf,
    const float* __restrict__ w_sk, const float* __restrict__ b_sk,
    const float* __restrict__ w_km, const float* __restrict__ b_km,
    float* __restrict__ out)
{
    __shared__ __half xd[Cc][NHALO];      // 23040 B: deformed halo, fp16
    __shared__ float  ovl[2304];          //  9216 B: xstage(fp16), later kmb|sknb
    __half* xstage = (__half*)ovl;        // [c][60] halves (7680 B)
    float* kmb    = ovl;                  // [128][9]
    float* sknb   = ovl + 128 * 9;        // [128][9]

    // XCD-aware swizzle: 2048 blocks -> contiguous 256-block chunk per XCD
    const int bid  = blockIdx.x;
    const int sw   = (bid & 7) * (NB / 8) + (bid >> 3);
    const int b    = sw >> 9;
    const int tile = sw & 511;
    const int ox = (tile & 15) * TW;
    const int oy = (tile >> 4) * TH;
    const int t  = threadIdx.x;
    const int syr = (oy >> 1) - 1;        // staged window origin (input coords)
    const int sxr = (ox >> 1) - 1;

    const float* xb = x + (size_t)b * Cc * HW;

    // ---- phase A: stage 6x10 input window, 64 ch, fp16 (border-clamped) ----
    for (int i = t; i < Cc * SN; i += 256) {          // 15 iters
        const int c   = i / SN;
        const int rem = i - c * SN;
        const int r   = rem / SXC;
        const int j   = rem - r * SXC;
        const int yy  = min(max(syr + r, 0), H0 - 1);
        const int xx  = min(max(sxr + j, 0), W0 - 1);
        xstage[i] = __float2half(xb[(size_t)c * HW + yy * W0 + xx]);
    }
    __syncthreads();

    // ---- phase B: bilinear sample halo -> xd (fp16), offsets via half2 ----
    for (int task = t; task < NTASK; task += 256) {
        const int g   = task / NHALO;
        const int pix = task - g * NHALO;
        const int hy  = pix / HX;
        const int hx  = pix - hy * HX;
        const int gy  = oy - 1 + hy;
        const int gx  = ox - 1 + hx;
        if (gy < 0 || gy >= HOc || gx < 0 || gx >= WOc) {
#pragma unroll 4
            for (int c = 0; c < CG; ++c) xd[g * CG + c][pix] = __half(0.f);
            continue;
        }
        const int sy = gy & 1, sx = gx & 1;
        const int h  = gy >> 1, w  = gx >> 1;
        const __half2 o2 = offbuf[((size_t)b * 16 + g * 4 + sy * 2 + sx) * HW
                                  + h * W0 + w];
        const float offx = __low2float(o2);
        const float offy = __high2float(o2);

        float ix = ((float)gx + 0.5f + offx) * 0.5f - 0.5f;
        float iy = ((float)gy + 0.5f + offy) * 0.5f - 0.5f;
        ix = fminf(fmaxf(ix, 0.f), (float)(W0 - 1));
        iy = fminf(fmaxf(iy, 0.f), (float)(H0 - 1));
        const float x0f = floorf(ix), y0f = floorf(iy);
        const float wx = ix - x0f,   wy = iy - y0f;
        const int x0 = (int)x0f, y0 = (int)y0f;
        const int x1 = min(x0 + 1, W0 - 1), y1 = min(y0 + 1, H0 - 1);
        const float w00 = (1.f - wx) * (1.f - wy);
        const float w01 = wx * (1.f - wy);
        const float w10 = (1.f - wx) * wy;
        const float w11 = wx * wy;

        const int j0 = x0 - sxr, j1 = x1 - sxr;
        const int i0 = y0 - syr, i1 = y1 - syr;
        const bool inl = (j0 >= 0) & (j1 < SXC) & (i0 >= 0) & (i1 < SYC);

        if (inl) {
            const int o00 = i0 * SXC + j0, o01 = i0 * SXC + j1;
            const int o10 = i1 * SXC + j0, o11 = i1 * SXC + j1;
            const __half* s = xstage + (g * CG) * SN;
#pragma unroll 4
            for (int c = 0; c < CG; ++c) {
                const __half* pc = s + c * SN;
                const float v = w00 * __half2float(pc[o00])
                              + w01 * __half2float(pc[o01])
                              + w10 * __half2float(pc[o10])
                              + w11 * __half2float(pc[o11]);
                xd[g * CG + c][pix] = __float2half(v);
            }
        } else {  // rare: tap escaped staged window -> global
            const int o00 = y0 * W0 + x0, o01 = y0 * W0 + x1;
            const int o10 = y1 * W0 + x0, o11 = y1 * W0 + x1;
            const float* xg = xb + (size_t)(g * CG) * HW;
#pragma unroll 4
            for (int c = 0; c < CG; ++c) {
                const float* pc = xg + (size_t)c * HW;
                const float v = w00 * pc[o00] + w01 * pc[o01]
                              + w10 * pc[o10] + w11 * pc[o11];
                xd[g * CG + c][pix] = __float2half(v);
            }
        }
    }
    __syncthreads();

    // ---- phase C: sk/km dots (wave-split), gate + softmax -> sknb ----
    {
        const int p   = t & 127;
        const int ctr = ((p >> 4) + 1) * HX + (p & 15) + 1;
        float acc[9];
#pragma unroll
        for (int k = 0; k < 9; ++k) acc[k] = 0.f;

        if (t < 128) {
            for (int c = 0; c < Cc; ++c) {
                const float xv = __half2float(xd[c][ctr]);
#pragma unroll
                for (int k = 0; k < 9; ++k)
                    acc[k] = fmaf(w_sk[k * Cc + c], xv, acc[k]);  // s_load
            }
        } else {
            for (int c = 0; c < Cc; ++c) {
                const float xv = __half2float(xd[c][ctr]);
#pragma unroll
                for (int k = 0; k < 9; ++k)
                    acc[k] = fmaf(w_km[k * Cc + c], xv, acc[k]);
            }
#pragma unroll
            for (int k = 0; k < 9; ++k) kmb[p * 9 + k] = acc[k];
        }
        __syncthreads();

        if (t < 128) {
            float sv[9], mx = -1e30f;
#pragma unroll
            for (int k = 0; k < 9; ++k) {
                const float z = kmb[p * 9 + k] + b_km[k];
                sv[k] = (acc[k] + b_sk[k]) / (1.f + __expf(-z));
                mx = fmaxf(mx, sv[k]);
            }
            float sum = 0.f;
#pragma unroll
            for (int k = 0; k < 9; ++k) { sv[k] = __expf(sv[k] - mx); sum += sv[k]; }
            const float inv = 1.f / sum;
#pragma unroll
            for (int k = 0; k < 9; ++k) sknb[p * 9 + k] = sv[k] * inv;
        }
    }
    __syncthreads();

    // ---- phase D: 3x3 dynamic conv, 2x2 pixel register blocking ----
    {
        const int sq    = t & 31;         // 8x4 squares of 2x2 pixels
        const int chunk = t >> 5;         // 8 channel chunks
        const int sqx = sq & 7, sqy = sq >> 3;
        const int hx0 = 2 * sqx, hy0 = 2 * sqy;
        const int p00 = (2 * sqy) * TW + 2 * sqx;

        float s00[9], s01[9], s10[9], s11[9];
#pragma unroll
        for (int k = 0; k < 9; ++k) {
            s00[k] = sknb[p00 * 9 + k];        s01[k] = sknb[(p00 + 1) * 9 + k];
            s10[k] = sknb[(p00 + TW) * 9 + k]; s11[k] = sknb[(p00 + TW + 1) * 9 + k];
        }
        const int orow0 = oy + 2 * sqy, ocol0 = ox + 2 * sqx;

#pragma unroll 2
        for (int i = 0; i < 8; ++i) {
            const int c = chunk * 8 + i;
            const __half* xc = &xd[c][0];
            float wd[4][4];
#pragma unroll
            for (int ry = 0; ry < 4; ++ry) {
                const int base = (hy0 + ry) * HX + hx0;
                const __half2 u0 = *reinterpret_cast<const __half2*>(&xc[base]);
                const __half2 u1 = *reinterpret_cast<const __half2*>(&xc[base + 2]);
                const float2 f0 = __half22float2(u0);
                const float2 f1 = __half22float2(u1);
                wd[ry][0] = f0.x; wd[ry][1] = f0.y; wd[ry][2] = f1.x; wd[ry][3] = f1.y;
            }
            float a00 = 0.f, a01 = 0.f, a10 = 0.f, a11 = 0.f;
#pragma unroll
            for (int ky = 0; ky < 3; ++ky)
#pragma unroll
                for (int kx = 0; kx < 3; ++kx) {
                    const int k = ky * 3 + kx;
                    a00 = fmaf(s00[k], wd[ky    ][kx    ], a00);
                    a01 = fmaf(s01[k], wd[ky    ][kx + 1], a01);
                    a10 = fmaf(s10[k], wd[ky + 1][kx    ], a10);
                    a11 = fmaf(s11[k], wd[ky + 1][kx + 1], a11);
                }
            float* ob = out + ((size_t)(b * Cc + c)) * (HOc * WOc)
                            + (size_t)orow0 * WOc + ocol0;
            *reinterpret_cast<float2*>(ob)       = make_float2(a00, a01);
            *reinterpret_cast<float2*>(ob + WOc) = make_float2(a10, a11);
        }
    }
}

// ---------------------------------------------------------------------------
extern "C" void kernel_launch(void* const* d_in, const int* in_sizes, int n_in,
                              void* d_out, int out_size, void* d_ws, size_t ws_size,
                              hipStream_t stream)
{
    const float* x      = (const float*)d_in[0];
    const float* w_off  = (const float*)d_in[1];
    const float* b_off  = (const float*)d_in[2];
    const float* w_offm = (const float*)d_in[3];
    const float* b_offm = (const float*)d_in[4];
    const float* w_sk   = (const float*)d_in[5];
    const float* b_sk   = (const float*)d_in[6];
    const float* w_km   = (const float*)d_in[7];
    const float* b_km   = (const float*)d_in[8];
    float* outp = (float*)d_out;

    const size_t off_bytes = (size_t)Bc * 16 * HW * sizeof(__half2); // 4 MiB
    if (ws_size < off_bytes) return;
    __half2* offbuf = (__half2*)d_ws;

    dim3 blk(256);
    dim3 g0(HW / 128, Bc);                // (128, 4): 128 px x 2 roles per block
    hipLaunchKernelGGL(k0_offsets, g0, blk, 0, stream,
                       x, w_off, b_off, w_offm, b_offm, offbuf);

    dim3 g1(NB);                          // 2048 blocks, XCD-swizzled in-kernel
    hipLaunchKernelGGL(k1_fused, g1, blk, 0, stream,
                       x, offbuf, w_sk, b_sk, w_km, b_km, outp);
}

// Round 6
// 74.611 us; speedup vs baseline: 2.0244x; 1.5941x over previous
//
#include <hip/hip_runtime.h>
#include <hip/hip_fp16.h>

constexpr int Bc  = 4;
constexpr int Cc  = 64;
constexpr int H0  = 128;
constexpr int W0  = 128;
constexpr int HW  = H0 * W0;
constexpr int Gc  = 4;
constexpr int CG  = Cc / Gc;     // 16
constexpr int HOc = H0 * 2;      // 256
constexpr int WOc = W0 * 2;      // 256

constexpr int TW = 16;           // output tile width
constexpr int TH = 8;            // output tile height
constexpr int HX = TW + 2;       // 18 halo cols
constexpr int HY = TH + 2;       // 10 halo rows
constexpr int NHALO = HX * HY;   // 180
constexpr int NTASK = Gc * NHALO;// 720

constexpr int SXC = 10;          // staged input cols (ox/2-1 .. ox/2+8)
constexpr int SYC = 6;           // staged input rows (oy/2-1 .. oy/2+4)
constexpr int SN  = SXC * SYC;   // 60 elems per channel

// ---------------------------------------------------------------------------
// k0: gated offset conv (unchanged from round 5 — measured ~1.6 us).
// Block = 128 pixels x 2 roles. Weights transposed in LDS, broadcast reads.
// Output: half2 (offx,offy) per (b, pair, pixel), 4 MB total.
// ---------------------------------------------------------------------------
__global__ __launch_bounds__(256) void k0_offsets(
    const float* __restrict__ x,
    const float* __restrict__ w_off,  const float* __restrict__ b_off,
    const float* __restrict__ w_offm, const float* __restrict__ b_offm,
    __half2* __restrict__ offbuf)
{
    __shared__ float wT[2][Cc][32];     // [mat][c][row] = 16 KB
    __shared__ float sig[128][33];      // sigmoid exchange, padded stride

    const int b    = blockIdx.y;
    const int t    = threadIdx.x;
    const int role = t >> 7;            // waves 0,1: w_off ; waves 2,3: w_offm
    const int pl   = t & 127;
    const int px   = blockIdx.x * 128 + pl;

    for (int i = t; i < 2 * Cc * 32; i += 256) {
        const int mat = i >> 11;
        const int c   = (i >> 5) & 63;
        const int r   = i & 31;
        wT[mat][c][r] = (mat ? w_offm : w_off)[r * Cc + c];
    }
    __syncthreads();

    float acc[32];
#pragma unroll
    for (int r = 0; r < 32; ++r) acc[r] = 0.f;

    const float* xp = x + (size_t)b * Cc * HW + px;
    for (int c = 0; c < Cc; ++c) {
        const float xv = xp[c * HW];                 // coalesced, once per b
        const float* wr = &wT[role][c][0];           // broadcast b128 reads
#pragma unroll
        for (int r = 0; r < 32; ++r)
            acc[r] = fmaf(wr[r], xv, acc[r]);
    }

    if (role == 1) {
#pragma unroll
        for (int r = 0; r < 32; ++r)
            sig[pl][r] = 1.f / (1.f + __expf(-(acc[r] + b_offm[r])));
    }
    __syncthreads();

    if (role == 0) {
#pragma unroll
        for (int rp = 0; rp < 16; ++rp) {
            const float vx = (acc[2 * rp]     + b_off[2 * rp])     * sig[pl][2 * rp];
            const float vy = (acc[2 * rp + 1] + b_off[2 * rp + 1]) * sig[pl][2 * rp + 1];
            offbuf[((size_t)b * 16 + rp) * HW + px] = __floats2half2_rn(vx, vy);
        }
    }
}

// ---------------------------------------------------------------------------
// k1_fused: round-3 structure (measured 55 us): fp32 xstage, 38.4 KB LDS,
// 4 blocks/CU, NO swizzle, plain launch bounds. Only delta: offsets read as
// one half2 instead of two scattered fp32 loads.
// ---------------------------------------------------------------------------
__global__ __launch_bounds__(256) void k1_fused(
    const float* __restrict__ x, const __half2* __restrict__ offbuf,
    const float* __restrict__ w_sk, const float* __restrict__ b_sk,
    const float* __restrict__ w_km, const float* __restrict__ b_km,
    float* __restrict__ out)
{
    __shared__ __half xd[Cc][NHALO];      // 23040 B: deformed halo, fp16
    __shared__ float  ovl[Cc * SN];       // 15360 B: xstage, later kmb|sknb
    float* xstage = ovl;                  // [c][60] fp32
    float* kmb    = ovl;                  // [128][9]
    float* sknb   = ovl + 128 * 9;        // [128][9]

    const int b    = blockIdx.y;
    const int tile = blockIdx.x;          // 16 x-tiles * 32 y-tiles
    const int ox = (tile & 15) * TW;
    const int oy = (tile >> 4) * TH;
    const int t  = threadIdx.x;
    const int syr = (oy >> 1) - 1;        // staged window origin (input coords)
    const int sxr = (ox >> 1) - 1;

    const float* xb = x + (size_t)b * Cc * HW;

    // ---- phase A: stage 6x10 input window, 64 ch, fp32 (border-clamped) ----
    for (int i = t; i < Cc * SN; i += 256) {          // 15 iters
        const int c   = i / SN;
        const int rem = i - c * SN;
        const int r   = rem / SXC;
        const int j   = rem - r * SXC;
        const int yy  = min(max(syr + r, 0), H0 - 1);
        const int xx  = min(max(sxr + j, 0), W0 - 1);
        xstage[i] = xb[(size_t)c * HW + yy * W0 + xx];
    }
    __syncthreads();

    // ---- phase B: bilinear sample halo -> xd (fp16), offsets via half2 ----
    for (int task = t; task < NTASK; task += 256) {
        const int g   = task / NHALO;
        const int pix = task - g * NHALO;
        const int hy  = pix / HX;
        const int hx  = pix - hy * HX;
        const int gy  = oy - 1 + hy;
        const int gx  = ox - 1 + hx;
        if (gy < 0 || gy >= HOc || gx < 0 || gx >= WOc) {
#pragma unroll 4
            for (int c = 0; c < CG; ++c) xd[g * CG + c][pix] = __half(0.f);
            continue;
        }
        const int sy = gy & 1, sx = gx & 1;
        const int h  = gy >> 1, w  = gx >> 1;
        const __half2 o2 = offbuf[((size_t)b * 16 + g * 4 + sy * 2 + sx) * HW
                                  + h * W0 + w];
        const float offx = __low2float(o2);
        const float offy = __high2float(o2);

        float ix = ((float)gx + 0.5f + offx) * 0.5f - 0.5f;
        float iy = ((float)gy + 0.5f + offy) * 0.5f - 0.5f;
        ix = fminf(fmaxf(ix, 0.f), (float)(W0 - 1));
        iy = fminf(fmaxf(iy, 0.f), (float)(H0 - 1));
        const float x0f = floorf(ix), y0f = floorf(iy);
        const float wx = ix - x0f,   wy = iy - y0f;
        const int x0 = (int)x0f, y0 = (int)y0f;
        const int x1 = min(x0 + 1, W0 - 1), y1 = min(y0 + 1, H0 - 1);
        const float w00 = (1.f - wx) * (1.f - wy);
        const float w01 = wx * (1.f - wy);
        const float w10 = (1.f - wx) * wy;
        const float w11 = wx * wy;

        const int j0 = x0 - sxr, j1 = x1 - sxr;
        const int i0 = y0 - syr, i1 = y1 - syr;
        const bool inl = (j0 >= 0) & (j1 < SXC) & (i0 >= 0) & (i1 < SYC);

        if (inl) {
            const int o00 = i0 * SXC + j0, o01 = i0 * SXC + j1;
            const int o10 = i1 * SXC + j0, o11 = i1 * SXC + j1;
            const float* s = xstage + (g * CG) * SN;
#pragma unroll 4
            for (int c = 0; c < CG; ++c) {
                const float* pc = s + c * SN;
                const float v = w00 * pc[o00] + w01 * pc[o01]
                              + w10 * pc[o10] + w11 * pc[o11];
                xd[g * CG + c][pix] = __float2half(v);
            }
        } else {  // rare: tap escaped staged window -> global
            const int o00 = y0 * W0 + x0, o01 = y0 * W0 + x1;
            const int o10 = y1 * W0 + x0, o11 = y1 * W0 + x1;
            const float* xg = xb + (size_t)(g * CG) * HW;
#pragma unroll 4
            for (int c = 0; c < CG; ++c) {
                const float* pc = xg + (size_t)c * HW;
                const float v = w00 * pc[o00] + w01 * pc[o01]
                              + w10 * pc[o10] + w11 * pc[o11];
                xd[g * CG + c][pix] = __float2half(v);
            }
        }
    }
    __syncthreads();

    // ---- phase C: sk/km dots (wave-split), gate + softmax -> sknb ----
    {
        const int p   = t & 127;
        const int ctr = ((p >> 4) + 1) * HX + (p & 15) + 1;
        float acc[9];
#pragma unroll
        for (int k = 0; k < 9; ++k) acc[k] = 0.f;

        if (t < 128) {
            for (int c = 0; c < Cc; ++c) {
                const float xv = __half2float(xd[c][ctr]);
#pragma unroll
                for (int k = 0; k < 9; ++k)
                    acc[k] = fmaf(w_sk[k * Cc + c], xv, acc[k]);  // s_load
            }
        } else {
            for (int c = 0; c < Cc; ++c) {
                const float xv = __half2float(xd[c][ctr]);
#pragma unroll
                for (int k = 0; k < 9; ++k)
                    acc[k] = fmaf(w_km[k * Cc + c], xv, acc[k]);
            }
#pragma unroll
            for (int k = 0; k < 9; ++k) kmb[p * 9 + k] = acc[k];
        }
        __syncthreads();

        if (t < 128) {
            float sv[9], mx = -1e30f;
#pragma unroll
            for (int k = 0; k < 9; ++k) {
                const float z = kmb[p * 9 + k] + b_km[k];
                sv[k] = (acc[k] + b_sk[k]) / (1.f + __expf(-z));
                mx = fmaxf(mx, sv[k]);
            }
            float sum = 0.f;
#pragma unroll
            for (int k = 0; k < 9; ++k) { sv[k] = __expf(sv[k] - mx); sum += sv[k]; }
            const float inv = 1.f / sum;
#pragma unroll
            for (int k = 0; k < 9; ++k) sknb[p * 9 + k] = sv[k] * inv;
        }
    }
    __syncthreads();

    // ---- phase D: 3x3 dynamic conv, 2x2 pixel register blocking ----
    {
        const int sq    = t & 31;         // 8x4 squares of 2x2 pixels
        const int chunk = t >> 5;         // 8 channel chunks
        const int sqx = sq & 7, sqy = sq >> 3;
        const int hx0 = 2 * sqx, hy0 = 2 * sqy;
        const int p00 = (2 * sqy) * TW + 2 * sqx;

        float s00[9], s01[9], s10[9], s11[9];
#pragma unroll
        for (int k = 0; k < 9; ++k) {
            s00[k] = sknb[p00 * 9 + k];        s01[k] = sknb[(p00 + 1) * 9 + k];
            s10[k] = sknb[(p00 + TW) * 9 + k]; s11[k] = sknb[(p00 + TW + 1) * 9 + k];
        }
        const int orow0 = oy + 2 * sqy, ocol0 = ox + 2 * sqx;

#pragma unroll 2
        for (int i = 0; i < 8; ++i) {
            const int c = chunk * 8 + i;
            const __half* xc = &xd[c][0];
            float wd[4][4];
#pragma unroll
            for (int ry = 0; ry < 4; ++ry) {
                const int base = (hy0 + ry) * HX + hx0;
                const __half2 u0 = *reinterpret_cast<const __half2*>(&xc[base]);
                const __half2 u1 = *reinterpret_cast<const __half2*>(&xc[base + 2]);
                const float2 f0 = __half22float2(u0);
                const float2 f1 = __half22float2(u1);
                wd[ry][0] = f0.x; wd[ry][1] = f0.y; wd[ry][2] = f1.x; wd[ry][3] = f1.y;
            }
            float a00 = 0.f, a01 = 0.f, a10 = 0.f, a11 = 0.f;
#pragma unroll
            for (int ky = 0; ky < 3; ++ky)
#pragma unroll
                for (int kx = 0; kx < 3; ++kx) {
                    const int k = ky * 3 + kx;
                    a00 = fmaf(s00[k], wd[ky    ][kx    ], a00);
                    a01 = fmaf(s01[k], wd[ky    ][kx + 1], a01);
                    a10 = fmaf(s10[k], wd[ky + 1][kx    ], a10);
                    a11 = fmaf(s11[k], wd[ky + 1][kx + 1], a11);
                }
            float* ob = out + ((size_t)(b * Cc + c)) * (HOc * WOc)
                            + (size_t)orow0 * WOc + ocol0;
            *reinterpret_cast<float2*>(ob)       = make_float2(a00, a01);
            *reinterpret_cast<float2*>(ob + WOc) = make_float2(a10, a11);
        }
    }
}

// ---------------------------------------------------------------------------
extern "C" void kernel_launch(void* const* d_in, const int* in_sizes, int n_in,
                              void* d_out, int out_size, void* d_ws, size_t ws_size,
                              hipStream_t stream)
{
    const float* x      = (const float*)d_in[0];
    const float* w_off  = (const float*)d_in[1];
    const float* b_off  = (const float*)d_in[2];
    const float* w_offm = (const float*)d_in[3];
    const float* b_offm = (const float*)d_in[4];
    const float* w_sk   = (const float*)d_in[5];
    const float* b_sk   = (const float*)d_in[6];
    const float* w_km   = (const float*)d_in[7];
    const float* b_km   = (const float*)d_in[8];
    float* outp = (float*)d_out;

    const size_t off_bytes = (size_t)Bc * 16 * HW * sizeof(__half2); // 4 MiB
    if (ws_size < off_bytes) return;
    __half2* offbuf = (__half2*)d_ws;

    dim3 blk(256);
    dim3 g0(HW / 128, Bc);                // (128, 4): 128 px x 2 roles per block
    hipLaunchKernelGGL(k0_offsets, g0, blk, 0, stream,
                       x, w_off, b_off, w_offm, b_offm, offbuf);

    dim3 g1(512, Bc);                     // 16x8 output tiles x b — NO swizzle
    hipLaunchKernelGGL(k1_fused, g1, blk, 0, stream,
                       x, offbuf, w_sk, b_sk, w_km, b_km, outp);
}